// Round 2
// baseline (594.797 us; speedup 1.0000x reference)
//
#include <hip/hip_runtime.h>

// MoE top-2 of 8 experts. T=4096 tokens, H=1024, F=4096.
// Pipeline: router -> scan(128-aligned expert regions) -> gather(x->bf16) ->
//           W transpose/convert to bf16 (BT layout) ->
//           grouped GEMM1 (relu) -> grouped GEMM2 -> combine.
#define T_TOK 4096
#define H_DIM 1024
#define F_DIM 4096
#define E_NUM 8
#define R_TOT 8192        // T * top_k rows
#define R_CAP 9216        // 128-aligned per-expert regions: max 71 tiles = 9088 rows

typedef short bf16x8 __attribute__((ext_vector_type(8)));
typedef float f32x4 __attribute__((ext_vector_type(4)));

__device__ inline unsigned short f2bf(float f) {   // RNE f32 -> bf16
  unsigned int u = __builtin_bit_cast(unsigned int, f);
  return (unsigned short)((u + 0x7FFFu + ((u >> 16) & 1u)) >> 16);
}

__device__ inline void async16(const void* g, void* l) {
  __builtin_amdgcn_global_load_lds((const __attribute__((address_space(1))) void*)g,
                                   (__attribute__((address_space(3))) void*)l, 16, 0, 0);
}

// ---------------- router: logits (fp64 acc), top-2, weights, counts ----------
__global__ __launch_bounds__(256) void router_k(
    const float* __restrict__ x, const float* __restrict__ Wr,
    const float* __restrict__ br, int* __restrict__ ctrl,
    int* __restrict__ t2i, float* __restrict__ t2w) {
  int lane = threadIdx.x & 63;
  int wid  = threadIdx.x >> 6;
  int t = blockIdx.x * 4 + wid;
  const float* xr = x + (size_t)t * H_DIM;
  double acc[E_NUM];
#pragma unroll
  for (int e = 0; e < E_NUM; e++) acc[e] = 0.0;
  for (int i = lane; i < H_DIM; i += 64) {
    float xv = xr[i];
    const float* wr = Wr + (size_t)i * E_NUM;
    float4 w0 = *(const float4*)wr;
    float4 w1 = *(const float4*)(wr + 4);
    acc[0] += (double)xv * w0.x; acc[1] += (double)xv * w0.y;
    acc[2] += (double)xv * w0.z; acc[3] += (double)xv * w0.w;
    acc[4] += (double)xv * w1.x; acc[5] += (double)xv * w1.y;
    acc[6] += (double)xv * w1.z; acc[7] += (double)xv * w1.w;
  }
#pragma unroll
  for (int e = 0; e < E_NUM; e++) {
    double v = acc[e];
    for (int off = 32; off > 0; off >>= 1) v += __shfl_down(v, off);
    acc[e] = v;
  }
  if (lane == 0) {
    float l[E_NUM];
#pragma unroll
    for (int e = 0; e < E_NUM; e++) l[e] = (float)acc[e] + br[e];
    int ia = 0; float la = l[0];
#pragma unroll
    for (int e = 1; e < E_NUM; e++) if (l[e] > la) { la = l[e]; ia = e; }
    int ib = -1; float lb = -3.4e38f;
#pragma unroll
    for (int e = 0; e < E_NUM; e++) if (e != ia && l[e] > lb) { lb = l[e]; ib = e; }
    // renormalized top-2 softmax weights: softmax denom cancels
    float w0 = 1.f / (1.f + __expf(lb - la));
    float w1 = 1.f - w0;
    t2i[2 * t] = ia; t2i[2 * t + 1] = ib;
    t2w[2 * t] = w0; t2w[2 * t + 1] = w1;
    atomicAdd(&ctrl[ia], 1);
    atomicAdd(&ctrl[ib], 1);
  }
}

// ------- scan: 128-ALIGNED offsets, cursors, row-tile table ------------------
// Alignment guarantees every 128-row GEMM tile lies inside ONE expert's
// region (no cross-expert overwrite). Pad rows are zeroed xg -> harmless.
__global__ void scan_k(int* ctrl) {
  if (threadIdx.x != 0) return;
  int off = 0, nt = 0;
  for (int e = 0; e < E_NUM; e++) {
    int c = ctrl[e];
    ctrl[8 + e]  = off;   // offset (128-aligned)
    ctrl[17 + e] = off;   // cursor
    int tiles = (c + 127) >> 7;
    for (int j = 0; j < tiles; j++) {
      ctrl[32 + 2 * nt] = e;
      ctrl[33 + 2 * nt] = off + j * 128;
      nt++;
    }
    off += tiles * 128;   // aligned advance
  }
  ctrl[16] = off;
  ctrl[25] = nt;
}

// ---------------- gather: x row -> bf16 row at expert-grouped position -------
__global__ __launch_bounds__(128) void gather_k(
    const float* __restrict__ x, const int* __restrict__ t2i,
    int* __restrict__ ctrl, int* __restrict__ row_map,
    unsigned short* __restrict__ xg) {
  int bid = blockIdx.x;  // (token, slot)
  __shared__ int srow;
  if (threadIdx.x == 0) {
    int e = t2i[bid];
    int row = atomicAdd(&ctrl[17 + e], 1);
    row_map[bid] = row;
    srow = row;
  }
  __syncthreads();
  int row = srow;
  int t = bid >> 1;
  const float* src = x + (size_t)t * H_DIM + threadIdx.x * 8;
  unsigned short* dst = xg + (size_t)row * H_DIM + threadIdx.x * 8;
  float4 v0 = *(const float4*)src;
  float4 v1 = *(const float4*)(src + 4);
  uint4 o;
  o.x = (unsigned int)f2bf(v0.x) | ((unsigned int)f2bf(v0.y) << 16);
  o.y = (unsigned int)f2bf(v0.z) | ((unsigned int)f2bf(v0.w) << 16);
  o.z = (unsigned int)f2bf(v1.x) | ((unsigned int)f2bf(v1.y) << 16);
  o.w = (unsigned int)f2bf(v1.z) | ((unsigned int)f2bf(v1.w) << 16);
  *(uint4*)dst = o;
}

// ---------------- transpose + fp32->bf16: in[E][R][C] -> out[E][C][R] --------
__global__ __launch_bounds__(256) void transpose_cvt_k(
    const float* __restrict__ in, unsigned short* __restrict__ out, int R, int C) {
  __shared__ unsigned short tile[64][68];
  size_t mat = (size_t)R * C;
  const float* ine = in + (size_t)blockIdx.z * mat;
  unsigned short* oute = out + (size_t)blockIdx.z * mat;
  int c0 = blockIdx.x * 64, r0 = blockIdx.y * 64;
  int tr = threadIdx.x >> 4, tc = threadIdx.x & 15;
#pragma unroll
  for (int p = 0; p < 4; p++) {
    int r = tr + p * 16;
    float4 v = *(const float4*)(ine + (size_t)(r0 + r) * C + c0 + tc * 4);
    tile[r][tc * 4 + 0] = f2bf(v.x);
    tile[r][tc * 4 + 1] = f2bf(v.y);
    tile[r][tc * 4 + 2] = f2bf(v.z);
    tile[r][tc * 4 + 3] = f2bf(v.w);
  }
  __syncthreads();
#pragma unroll
  for (int p = 0; p < 4; p++) {
    int c = tr + p * 16;
    unsigned int u0 = (unsigned int)tile[tc * 4 + 0][c] | ((unsigned int)tile[tc * 4 + 1][c] << 16);
    unsigned int u1 = (unsigned int)tile[tc * 4 + 2][c] | ((unsigned int)tile[tc * 4 + 3][c] << 16);
    uint2 o = make_uint2(u0, u1);
    *(uint2*)(oute + (size_t)(c0 + c) * R + r0 + tc * 4) = o;
  }
}

// ---------------- grouped BT GEMM: C[m][n] = A[m][k] * B[n][k] ---------------
// 128x128 tile, BK=32, 4 waves (2x2), 16x16x32 bf16 MFMA, m97 2-barrier loop.
template <bool RELU, bool OUTF32>
__global__ __launch_bounds__(256) void gemm_bt_k(
    const int* __restrict__ ctrl, const unsigned short* __restrict__ A,
    const unsigned short* __restrict__ Bw, const float* __restrict__ bias,
    void* __restrict__ Cout, int K, int N) {
  int rt = blockIdx.y;
  if (rt >= ctrl[25]) return;
  int e = ctrl[32 + 2 * rt];
  int row0 = ctrl[33 + 2 * rt];
  __shared__ unsigned short lA[128 * 32];
  __shared__ unsigned short lB[128 * 32];
  const unsigned short* Ae = A + (size_t)row0 * K;
  const unsigned short* Be = Bw + (size_t)e * ((size_t)N * K) + (size_t)blockIdx.x * 128 * K;
  int tid = threadIdx.x;
  int lane = tid & 63, wid = tid >> 6;
  int wm = wid >> 1, wn = wid & 1;
  int stR = tid >> 2, stC = (tid & 3) * 8;   // staging: 16B per thread, 2 passes
  f32x4 zero4 = {0.f, 0.f, 0.f, 0.f};
  f32x4 acc[4][4];
#pragma unroll
  for (int m = 0; m < 4; m++)
#pragma unroll
    for (int n = 0; n < 4; n++) acc[m][n] = zero4;
  int lr = lane & 15, kg = lane >> 4;
  for (int kt = 0; kt < K; kt += 32) {
    __syncthreads();
    async16(Ae + (size_t)stR * K + kt + stC,        lA + (size_t)tid * 8);
    async16(Ae + (size_t)(stR + 64) * K + kt + stC, lA + 2048 + (size_t)tid * 8);
    async16(Be + (size_t)stR * K + kt + stC,        lB + (size_t)tid * 8);
    async16(Be + (size_t)(stR + 64) * K + kt + stC, lB + 2048 + (size_t)tid * 8);
    __syncthreads();
    bf16x8 a[4], b[4];
#pragma unroll
    for (int m = 0; m < 4; m++)
      a[m] = *(const bf16x8*)(lA + (size_t)(wm * 64 + m * 16 + lr) * 32 + kg * 8);
#pragma unroll
    for (int n = 0; n < 4; n++)
      b[n] = *(const bf16x8*)(lB + (size_t)(wn * 64 + n * 16 + lr) * 32 + kg * 8);
#pragma unroll
    for (int m = 0; m < 4; m++)
#pragma unroll
      for (int n = 0; n < 4; n++)
        acc[m][n] = __builtin_amdgcn_mfma_f32_16x16x32_bf16(a[m], b[n], acc[m][n], 0, 0, 0);
  }
  // epilogue: C row = (lane>>4)*4+q, col = lane&15 (per-frag), + bias (+relu)
  int n0 = blockIdx.x * 128;
  const float* be = bias + (size_t)e * N;
#pragma unroll
  for (int m = 0; m < 4; m++) {
#pragma unroll
    for (int q = 0; q < 4; q++) {
      int lrow = wm * 64 + m * 16 + (lane >> 4) * 4 + q;
      size_t rowoff = (size_t)(row0 + lrow) * N;
#pragma unroll
      for (int n = 0; n < 4; n++) {
        int col = n0 + wn * 64 + n * 16 + (lane & 15);
        float v = acc[m][n][q] + be[col];
        if (RELU) v = fmaxf(v, 0.f);
        if (OUTF32) ((float*)Cout)[rowoff + col] = v;
        else ((unsigned short*)Cout)[rowoff + col] = f2bf(v);
      }
    }
  }
}

// ---------------- combine: out[t] = w0*y[r0] + w1*y[r1] ----------------------
__global__ __launch_bounds__(256) void combine_k(
    const float* __restrict__ y, const int* __restrict__ row_map,
    const float* __restrict__ t2w, float* __restrict__ out) {
  int t = blockIdx.x;
  int i = threadIdx.x * 4;
  int r0 = row_map[2 * t], r1 = row_map[2 * t + 1];
  float w0 = t2w[2 * t], w1 = t2w[2 * t + 1];
  float4 a = *(const float4*)(y + (size_t)r0 * H_DIM + i);
  float4 b = *(const float4*)(y + (size_t)r1 * H_DIM + i);
  float4 o;
  o.x = w0 * a.x + w1 * b.x;
  o.y = w0 * a.y + w1 * b.y;
  o.z = w0 * a.z + w1 * b.z;
  o.w = w0 * a.w + w1 * b.w;
  *(float4*)(out + (size_t)t * H_DIM + i) = o;
}

extern "C" void kernel_launch(void* const* d_in, const int* in_sizes, int n_in,
                              void* d_out, int out_size, void* d_ws, size_t ws_size,
                              hipStream_t stream) {
  const float* x  = (const float*)d_in[0];
  const float* Wr = (const float*)d_in[1];
  const float* br = (const float*)d_in[2];
  const float* W1 = (const float*)d_in[3];
  const float* b1 = (const float*)d_in[4];
  const float* W2 = (const float*)d_in[5];
  const float* b2 = (const float*)d_in[6];
  float* out = (float*)d_out;

  char* ws = (char*)d_ws;
  int*   ctrl    = (int*)ws;                      // 1024 ints: counts/offs/cursors/ntiles/table
  int*   t2i     = (int*)(ws + 4096);             // 8192 ints
  float* t2w     = (float*)(ws + 4096 + 32768);   // 8192 floats
  int*   row_map = (int*)(ws + 4096 + 65536);     // 8192 ints
  size_t off = (size_t)1 << 20;
  unsigned short* WT1 = (unsigned short*)(ws + off); off += (size_t)E_NUM * F_DIM * H_DIM * 2;
  unsigned short* WT2 = (unsigned short*)(ws + off); off += (size_t)E_NUM * H_DIM * F_DIM * 2;
  unsigned short* xg  = (unsigned short*)(ws + off); off += (size_t)R_CAP * H_DIM * 2;
  unsigned short* hb  = (unsigned short*)(ws + off); off += (size_t)R_CAP * F_DIM * 2;
  float*          yb  = (float*)(ws + off);          off += (size_t)R_CAP * H_DIM * 4;

  if (ws_size < off) {  // not enough scratch: fail visibly, don't corrupt memory
    hipMemsetAsync(d_out, 0, (size_t)out_size * 4, stream);
    return;
  }

  hipMemsetAsync(ctrl, 0, 4096, stream);
  hipMemsetAsync(xg, 0, (size_t)R_CAP * H_DIM * 2, stream);  // pad rows deterministic zeros
  // weight transpose+convert (independent of routing)
  transpose_cvt_k<<<dim3(F_DIM / 64, H_DIM / 64, E_NUM), 256, 0, stream>>>(W1, WT1, H_DIM, F_DIM);
  transpose_cvt_k<<<dim3(H_DIM / 64, F_DIM / 64, E_NUM), 256, 0, stream>>>(W2, WT2, F_DIM, H_DIM);
  router_k<<<dim3(T_TOK / 4), 256, 0, stream>>>(x, Wr, br, ctrl, t2i, t2w);
  scan_k<<<dim3(1), 64, 0, stream>>>(ctrl);
  gather_k<<<dim3(R_TOT), 128, 0, stream>>>(x, t2i, ctrl, row_map, xg);
  // GEMM1: h = relu(xg @ W1 + b1)   [rows x F], bf16 out
  gemm_bt_k<true, false><<<dim3(F_DIM / 128, 72), 256, 0, stream>>>(ctrl, xg, WT1, b1, hb, H_DIM, F_DIM);
  // GEMM2: y = h @ W2 + b2          [rows x H], fp32 out
  gemm_bt_k<false, true><<<dim3(H_DIM / 128, 72), 256, 0, stream>>>(ctrl, hb, WT2, b2, yb, F_DIM, H_DIM);
  combine_k<<<dim3(T_TOK), 256, 0, stream>>>(yb, row_map, t2w, out);
}